// Round 22
// baseline (1346.993 us; speedup 1.0000x reference)
//
#include <hip/hip_runtime.h>
#include <math.h>

#define BB 32
#define SS 2048
#define HH 1024
#define MT (BB*SS)      // 65536 rows

#define BM 128
#define BN 256
#define BK 64           // fp32 k per GEMM tile (two 32-k B_pre tiles)
#define NKT (HH/BK)     // 16 k-tiles in the GEMM loop
#define NT32 32         // B_pre is built in 32-k tiles (writer unchanged)
#define NCH (HH/BN)     // 4 n-chunks
#define THREADS 512     // 8 waves (2m x 4n), per-wave 64x64; 2 blocks/CU
// B_pre per (nch,kt32) tile: 2 planes x 16 frags x 512 u16 = 16384 u16 (32KB)
#define BTILE 16384

typedef float  f32x4 __attribute__((ext_vector_type(4)));
typedef short  s16x8 __attribute__((ext_vector_type(8)));
typedef unsigned short u16;

// truncation split: x ~= hi + lo, |x - hi - lo| <= 2^-16 |x|
__device__ inline void split1(float x, u16& h, u16& l) {
    unsigned u = __float_as_uint(x);
    h = (u16)(u >> 16);
    float hf = __uint_as_float((u >> 16) << 16);
    l = (u16)(__float_as_uint(x - hf) >> 16);
}
__device__ inline void split8v(float4 v0, float4 v1, s16x8& h, s16x8& l) {
    float x[8] = {v0.x,v0.y,v0.z,v0.w,v1.x,v1.y,v1.z,v1.w};
    #pragma unroll
    for (int j = 0; j < 8; ++j) {
        u16 hh, ll; split1(x[j], hh, ll);
        h[j] = (short)hh; l[j] = (short)ll;
    }
}

// ---------------- Kernel 1: dec_proj[b][n] = dh[b]·Wa_w[:,n] + Wa_b[n] + Ua_b[n]
__global__ void dec_proj_kernel(const float* __restrict__ dh,
                                const float* __restrict__ Wa_w,
                                const float* __restrict__ Wa_b,
                                const float* __restrict__ Ua_b,
                                float* __restrict__ dec_proj) {
    __shared__ float sdh[HH];
    const int b   = blockIdx.x;
    const int nq  = blockIdx.y;           // 0..7
    const int tid = threadIdx.x;          // 128
    #pragma unroll
    for (int i = 0; i < 2; ++i)
        *(float4*)&sdh[(tid + i*128)*4] =
            *(const float4*)&dh[b*HH + (tid + i*128)*4];
    __syncthreads();
    const int n = nq*128 + tid;
    float a0 = 0.f, a1 = 0.f, a2 = 0.f, a3 = 0.f;
    for (int k = 0; k < HH; k += 4) {
        a0 = fmaf(sdh[k+0], Wa_w[(size_t)(k+0)*HH + n], a0);
        a1 = fmaf(sdh[k+1], Wa_w[(size_t)(k+1)*HH + n], a1);
        a2 = fmaf(sdh[k+2], Wa_w[(size_t)(k+2)*HH + n], a2);
        a3 = fmaf(sdh[k+3], Wa_w[(size_t)(k+3)*HH + n], a3);
    }
    dec_proj[b*HH + n] = ((a0 + a1) + (a2 + a3)) + Wa_b[n] + Ua_b[n];
}

// ---------------- Kernel 2: Ua [K][N] -> B_pre frag-linear split-bf16 image
// (r5/r11-verified 16x16 image; unchanged — GEMM consumes 32-k tile PAIRS)
// B_pre[(nch*NT32+kt)*16384 + plane*8192 + f*512 + (c*16+lr)*8 + j]
__global__ void transpose_convert_kernel(const float* __restrict__ Ua,
                                         u16* __restrict__ B_pre) {
    __shared__ u16 shh[64][72], shl[64][72];
    const int nb = blockIdx.x * 64, kb = blockIdx.y * 64;
    const int tid = threadIdx.x;          // 256
    const int kl = tid >> 4, nl4 = (tid & 15) * 4;
    #pragma unroll
    for (int q = 0; q < 4; ++q) {
        const int k = kl + q*16;
        float4 v = *(const float4*)&Ua[(size_t)(kb + k)*HH + nb + nl4];
        float x[4] = {v.x, v.y, v.z, v.w};
        #pragma unroll
        for (int j = 0; j < 4; ++j) {
            u16 hh, ll; split1(x[j], hh, ll);
            shh[k][nl4 + j] = hh; shl[k][nl4 + j] = ll;
        }
    }
    __syncthreads();
    const int nl = tid >> 3, kc8 = (tid & 7) * 8;
    #pragma unroll
    for (int q = 0; q < 2; ++q) {
        const int n = nb + nl + q*32;
        const int kglob = kb + kc8;
        s16x8 hv, lv;
        #pragma unroll
        for (int j = 0; j < 8; ++j) {
            hv[j] = (short)shh[kc8 + j][nl + q*32];
            lv[j] = (short)shl[kc8 + j][nl + q*32];
        }
        const int nchI = n >> 8, fI = (n >> 4) & 15, lrI = n & 15;
        const int ktI = kglob >> 5, cI = (kglob >> 3) & 3;
        const size_t base = (size_t)(nchI*NT32 + ktI) * BTILE;
        const size_t idxH = base + fI*512 + (cI*16 + lrI)*8;
        *(s16x8*)&B_pre[idxH]        = hv;
        *(s16x8*)&B_pre[idxH + 8192] = lv;
    }
}

// ---------------- Kernel 3: split-bf16 3-product MFMA GEMM, 16x16x32, BK=64
// r19/r21 free-run structure EXACTLY (one raw barrier per tile, lgkmcnt(0)
// only -- no vmcnt drain; B direct-from-L2 prefetched one tile ahead; A
// reg-staged with write-linear 0-conflict maps; 2 blocks/CU). ONE change:
// BK 32->64 halves the tile count (32->16), halving the per-tile fixed cost
// (barrier resync + waits + staging bursts) that r21's cycle audit showed
// as ~870 of 1804 cyc per wave-tile against a 933-cyc MFMA floor.
// A image per buf: [f8][ks2][c4][r16] lane-major (group g = f*128+ks*64+
// c*16+r at g*8 u16). Thread stages groups g=tid, tid+512: write at tid*16B
// and tid*16B+8KB (block-linear, 0-conflict); frag (f,ks) read at
// f*1024+ks*512+lane*8 (contiguous 1KB, 0-conflict).
__global__ __launch_bounds__(THREADS, 4)
void gemm_fr_kernel(const float* __restrict__ A,        // enc [M, K] fp32
                    const u16* __restrict__ B_pre,      // frag-linear split image
                    const float* __restrict__ dec_proj, // [B, H] (biases folded)
                    const float* __restrict__ Va_w,     // [H]
                    float* __restrict__ partials)       // [M, 16]
{
    __shared__ __align__(16) u16 AhS[2][BM*BK];   // 2 x 16KB
    __shared__ __align__(16) u16 AlS[2][BM*BK];   // 2 x 16KB

    // XCD-chunked bijective swizzle: 2048 blocks, 256 per XCD;
    // nch fastest -> 4 consecutive blocks share each A panel via L2.
    const int bid = blockIdx.x;
    const int wg  = (bid & 7) * 256 + (bid >> 3);
    const int nch = wg & 3;
    const int mt  = wg >> 2;                  // 0..511
    const int m0  = mt * BM, n0 = nch * BN;

    const int tid = threadIdx.x, lane = tid & 63, wid = tid >> 6;
    const int wm = wid >> 2, wn = wid & 3;    // 2 x 4 waves, per-wave 64x64
    const int lr = lane & 15, lk = lane >> 4;

    // A staging: groups g0=tid, g1=tid+512; g -> f=g>>7, ks=(g>>6)&1,
    // c=(g>>4)&3, r=g&15; global A[m0+f*16+r][ks*32+c*8 .. +7].
    const int g0 = tid, g1 = tid + 512;
    const float* Ab0 = A + (size_t)(m0 + (g0>>7)*16 + (g0&15))*HH
                         + ((g0>>6)&1)*32 + ((g0>>4)&3)*8;
    const float* Ab1 = A + (size_t)(m0 + (g1>>7)*16 + (g1&15))*HH
                         + ((g1>>6)&1)*32 + ((g1>>4)&3)*8;
    const int aw0 = tid*8, aw1 = tid*8 + 4096;   // u16 units (linear writes)
    // B direct-from-global base: wave reads 4 frag pairs per 32-k tile
    const u16* Bt = B_pre + (size_t)nch*NT32*BTILE + (wn*4)*512 + lane*8;

    f32x4 acc[4][4];
    #pragma unroll
    for (int i = 0; i < 4; ++i)
        #pragma unroll
        for (int j = 0; j < 4; ++j) acc[i][j] = (f32x4){0.f,0.f,0.f,0.f};

    s16x8  bh[4][2], bl[4][2];    // B frags [nf][ks] (64 VGPR)
    float4 a0_, a1_, a2_, a3_;    // A staging regs (16 VGPR)

    auto loadA = [&](int kt) {      // kt in 64-k units
        const float* p0 = Ab0 + kt*BK;
        const float* p1 = Ab1 + kt*BK;
        a0_ = *(const float4*)(p0 + 0);
        a1_ = *(const float4*)(p0 + 4);
        a2_ = *(const float4*)(p1 + 0);
        a3_ = *(const float4*)(p1 + 4);
    };
    auto writeA = [&](int db) {
        s16x8 h, l;
        split8v(a0_, a1_, h, l);
        *(s16x8*)&AhS[db][aw0] = h; *(s16x8*)&AlS[db][aw0] = l;
        split8v(a2_, a3_, h, l);
        *(s16x8*)&AhS[db][aw1] = h; *(s16x8*)&AlS[db][aw1] = l;
    };
    auto readB = [&](int kt) {      // kt in 64-k units -> 32-k tiles 2kt,2kt+1
        const u16* p0 = Bt + (size_t)(2*kt    )*BTILE;
        const u16* p1 = Bt + (size_t)(2*kt + 1)*BTILE;
        #pragma unroll
        for (int q = 0; q < 4; ++q) {
            bh[q][0] = *(const s16x8*)(p0 + q*512);
            bl[q][0] = *(const s16x8*)(p0 + 8192 + q*512);
            bh[q][1] = *(const s16x8*)(p1 + q*512);
            bl[q][1] = *(const s16x8*)(p1 + 8192 + q*512);
        }
    };

    // prologue: stage A tile 0 into buf 0; B(0) into regs
    loadA(0);
    writeA(0);
    readB(0);
    __syncthreads();            // one full drain outside the loop is fine
    loadA(1);                   // A(1) regs held through iter 0

    for (int j = 0; j < NKT; ++j) {
        const int cb = j & 1;
        const bool hn = (j + 1 < NKT);

        #pragma unroll
        for (int f = 0; f < 4; ++f) {
            const int o = (wm*4 + f)*1024 + lane*8;   // frag (f,ks)
            const s16x8 ah0 = *(const s16x8*)&AhS[cb][o];
            const s16x8 al0 = *(const s16x8*)&AlS[cb][o];
            const s16x8 ah1 = *(const s16x8*)&AhS[cb][o + 512];
            const s16x8 al1 = *(const s16x8*)&AlS[cb][o + 512];
            __builtin_amdgcn_s_setprio(1);
            #pragma unroll
            for (int q = 0; q < 4; ++q) {
                f32x4 c = acc[f][q];
                c = __builtin_amdgcn_mfma_f32_16x16x32_bf16(ah0, bh[q][0], c, 0, 0, 0);
                c = __builtin_amdgcn_mfma_f32_16x16x32_bf16(ah0, bl[q][0], c, 0, 0, 0);
                c = __builtin_amdgcn_mfma_f32_16x16x32_bf16(al0, bh[q][0], c, 0, 0, 0);
                c = __builtin_amdgcn_mfma_f32_16x16x32_bf16(ah1, bh[q][1], c, 0, 0, 0);
                c = __builtin_amdgcn_mfma_f32_16x16x32_bf16(ah1, bl[q][1], c, 0, 0, 0);
                c = __builtin_amdgcn_mfma_f32_16x16x32_bf16(al1, bh[q][1], c, 0, 0, 0);
                acc[f][q] = c;
            }
            __builtin_amdgcn_s_setprio(0);
        }
        // tail staging: B prefetch first (WAR on bh/bl is free), then A
        if (hn) {
            readB(j + 1);                          // spans tail+barrier -> hidden
            writeA(cb ^ 1);                        // a-regs loaded 1 tile ago
            loadA(j + 2 < NKT ? j + 2 : j + 1);    // stays in flight past barrier
        }
        // raw barrier: publish ds_writes only; NO vmcnt drain (T4)
        asm volatile("s_waitcnt lgkmcnt(0)" ::: "memory");
        __builtin_amdgcn_sched_barrier(0);
        __builtin_amdgcn_s_barrier();
        __builtin_amdgcn_sched_barrier(0);
    }

    // epilogue: rowsum over this wave's 64 n-cols of Va[n]*tanh(C+dp[n])
    // 16x16 C layout (verified): col=lane&15, row=(lane>>4)*4+reg
    const int bidx = m0 >> 11;            // batch index (2048 rows per batch)
    float dp[4], va[4];
    #pragma unroll
    for (int j = 0; j < 4; ++j) {
        const int n = n0 + wn*64 + j*16 + lr;
        dp[j] = dec_proj[bidx*HH + n];
        va[j] = Va_w[n];
    }
    #pragma unroll
    for (int f = 0; f < 4; ++f) {
        #pragma unroll
        for (int r = 0; r < 4; ++r) {
            float s = 0.f;
            #pragma unroll
            for (int j = 0; j < 4; ++j)
                s += va[j] * tanhf(acc[f][j][r] + dp[j]);
            s += __shfl_xor(s, 1, 64);
            s += __shfl_xor(s, 2, 64);
            s += __shfl_xor(s, 4, 64);
            s += __shfl_xor(s, 8, 64);
            if (lr == 0) {
                const int m = m0 + wm*64 + f*16 + lk*4 + r;
                partials[(size_t)m*16 + nch*4 + wn] = s;
            }
        }
    }
}

// ---------------- Kernel 4: sum 16 partials + Va_b, mask, softmax over S
__global__ void softmax_kernel(const float* __restrict__ partials,
                               const int* __restrict__ mask,
                               const float* __restrict__ vb_ptr,
                               float* __restrict__ out)
{
    const int b   = blockIdx.x;
    const int tid = threadIdx.x;   // 256, each handles 8 s-positions
    __shared__ float sred[8];
    const float vb = vb_ptr[0];
    float sc[8];
    float mymax = -INFINITY;
    #pragma unroll
    for (int i = 0; i < 8; ++i) {
        const int s = i*256 + tid;
        const float4* p = (const float4*)&partials[((size_t)b*SS + s)*16];
        const float4 x = p[0], y = p[1], z = p[2], w = p[3];
        float v = (((x.x+x.y)+(x.z+x.w)) + ((y.x+y.y)+(y.z+y.w)))
                + (((z.x+z.y)+(z.z+z.w)) + ((w.x+w.y)+(w.z+w.w))) + vb;
        if (mask[b*SS + s] == 0) v = -1e9f;
        sc[i] = v;
        mymax = fmaxf(mymax, v);
    }
    #pragma unroll
    for (int off = 1; off < 64; off <<= 1)
        mymax = fmaxf(mymax, __shfl_xor(mymax, off, 64));
    const int wave = tid >> 6, lane = tid & 63;
    if (lane == 0) sred[wave] = mymax;
    __syncthreads();
    const float bmax = fmaxf(fmaxf(sred[0], sred[1]), fmaxf(sred[2], sred[3]));
    float ex[8], mysum = 0.f;
    #pragma unroll
    for (int i = 0; i < 8; ++i) {
        ex[i] = __expf(sc[i] - bmax);
        mysum += ex[i];
    }
    #pragma unroll
    for (int off = 1; off < 64; off <<= 1)
        mysum += __shfl_xor(mysum, off, 64);
    if (lane == 0) sred[4 + wave] = mysum;
    __syncthreads();
    const float inv = 1.f / (sred[4] + sred[5] + sred[6] + sred[7]);
    #pragma unroll
    for (int i = 0; i < 8; ++i)
        out[(size_t)b*SS + i*256 + tid] = ex[i] * inv;
}

extern "C" void kernel_launch(void* const* d_in, const int* in_sizes, int n_in,
                              void* d_out, int out_size, void* d_ws, size_t ws_size,
                              hipStream_t stream) {
    const float* dh   = (const float*)d_in[0];
    const float* enc  = (const float*)d_in[1];
    const int*   mask = (const int*)d_in[2];
    const float* Wa_w = (const float*)d_in[3];
    const float* Wa_b = (const float*)d_in[4];
    const float* Ua_w = (const float*)d_in[5];
    const float* Ua_b = (const float*)d_in[6];
    const float* Va_w = (const float*)d_in[7];
    const float* Va_b = (const float*)d_in[8];
    float* out = (float*)d_out;

    float* dec_proj = (float*)d_ws;                       // [B,H]    128 KB
    float* partials = dec_proj + BB*HH;                   // [M,16]   4 MB
    u16*   B_pre    = (u16*)(partials + (size_t)MT*16);   // frag-linear, 4 MB

    dec_proj_kernel<<<dim3(BB, 8), 128, 0, stream>>>(dh, Wa_w, Wa_b, Ua_b, dec_proj);
    transpose_convert_kernel<<<dim3(HH/64, HH/64), 256, 0, stream>>>(Ua_w, B_pre);
    gemm_fr_kernel<<<(MT/BM)*NCH, THREADS, 0, stream>>>(enc, B_pre, dec_proj, Va_w, partials);
    softmax_kernel<<<BB, 256, 0, stream>>>(partials, mask, Va_b, out);
}